// Round 13
// baseline (34.265 us; speedup 1.0000x reference)
//
#include <hip/hip_runtime.h>
#include <hip/hip_bf16.h>

#define NND 2000
#define KNB 16
#define CS 128
#define CZ 64
#define NE (NND*KNB)

typedef __attribute__((ext_vector_type(8))) short short8;
typedef __attribute__((ext_vector_type(4))) float f32x4;
typedef __attribute__((ext_vector_type(2))) unsigned int uint2v;
typedef __attribute__((ext_vector_type(4))) unsigned int uint4v;

// hardware bf16 convert (compiler emits v_cvt_pk_bf16_f32; RNE)
__device__ __forceinline__ unsigned int pk2(float a, float b) {
  __hip_bfloat162 h = __float22bfloat162_rn(make_float2(a, b));
  unsigned int u;
  __builtin_memcpy(&u, &h, 4);
  return u;
}
__device__ __forceinline__ unsigned short bfc(float f) {
  __hip_bfloat16 h = __float2bfloat16(f);
  unsigned short u;
  __builtin_memcpy(&u, &h, 2);
  return u;
}

__device__ __forceinline__ float fexp2(float x) {
#if __has_builtin(__builtin_amdgcn_exp2f)
  return __builtin_amdgcn_exp2f(x);
#else
  return __expf(0.6931471805599453f * x);
#endif
}

// ---------------------------------------------------------------------------
// Precompute (r12, unchanged):
//   blocks [0,500): E1 = exp(-(nf@wg1 + b_gate)), E2 = exp(-(nf@wg2)),
//     w_gate staged once per block into 64KB LDS.
//   block 500: wave0 bias2; wave1 wdbF; wave2 wedF; wave3 woF (bf16 frags).
// ---------------------------------------------------------------------------
__global__ __launch_bounds__(256) void precompute_kernel(
    const float* __restrict__ nf,
    const float* __restrict__ w_gate, const float* __restrict__ b_gate,
    const float* __restrict__ ln_b, const float* __restrict__ w_out,
    const float* __restrict__ b_out,
    const float* __restrict__ w_db, const float* __restrict__ w_edge,
    const float* __restrict__ ln_g,
    float* __restrict__ g1, float* __restrict__ g2, float* __restrict__ bias2,
    unsigned short* __restrict__ wdbF, unsigned short* __restrict__ wedF,
    unsigned short* __restrict__ woF)
{
  __shared__ float wl[2*CS][CZ];        // 64 KB: w_gate staged per block
  const int p = threadIdx.x;
  const int lane = p & 63;
  const int wv   = p >> 6;
  const int b    = blockIdx.x;
  if (b < NND/4) {
    #pragma unroll
    for (int t = 0; t < 16; ++t) {
      const int e = (p + 256*t) * 4;
      const f32x4 x = *(const f32x4*)&w_gate[e];
      *(f32x4*)&wl[e >> 6][e & 63] = x;
    }
    __syncthreads();

    const int v = b*4 + wv;
    const float* nrow = nf + v*CS;
    float a10=0.f,a11=0.f,a12=0.f,a13=0.f;
    float a20=0.f,a21=0.f,a22=0.f,a23=0.f;
    #pragma unroll
    for (int cc = 0; cc < CS; cc += 4) {
      const f32x4 x = *(const f32x4*)&nrow[cc];
      a10 = fmaf(x[0], wl[cc+0][lane], a10);
      a11 = fmaf(x[1], wl[cc+1][lane], a11);
      a12 = fmaf(x[2], wl[cc+2][lane], a12);
      a13 = fmaf(x[3], wl[cc+3][lane], a13);
      a20 = fmaf(x[0], wl[CS+cc+0][lane], a20);
      a21 = fmaf(x[1], wl[CS+cc+1][lane], a21);
      a22 = fmaf(x[2], wl[CS+cc+2][lane], a22);
      a23 = fmaf(x[3], wl[CS+cc+3][lane], a23);
    }
    const float a1 = b_gate[lane] + ((a10+a11)+(a12+a13));
    const float a2 = (a20+a21)+(a22+a23);
    g1[v*CZ + lane] = fexp2(a1 * -1.4426950408889634f);
    g2[v*CZ + lane] = fexp2(a2 * -1.4426950408889634f);
  } else {
    if (wv == 0) {
      float a = b_out[lane];
      #pragma unroll
      for (int cc = 0; cc < CZ; ++cc)
        a = fmaf(ln_b[cc], w_out[cc*CZ + lane], a);
      bias2[lane] = a;
    } else if (wv == 1) {
      for (int e = lane; e < 4096; e += 64) {
        const int entry = e >> 3, t = e & 7;
        const int l2 = entry & 63, sn = entry >> 6;
        const int s = sn >> 2, nt = sn & 3;
        const int q2 = l2 >> 4, c2 = l2 & 15;
        wdbF[e] = bfc(w_db[(32*s + 8*q2 + t)*CZ + 16*nt + c2]);
      }
    } else if (wv == 2) {
      for (int e = lane; e < 4096; e += 64) {
        const int entry = e >> 3, t = e & 7;
        const int p2 = entry & 255, s = entry >> 8;
        const int q2 = (p2 >> 4) & 3, c2 = p2 & 15;
        wedF[e] = bfc(w_edge[(32*s + 8*q2 + t)*CZ + 16*(p2 >> 6) + c2]);
      }
    } else {
      for (int e = lane; e < 4096; e += 64) {
        const int entry = e >> 3, t = e & 7;
        const int p2 = entry & 255, s = entry >> 8;
        const int q2 = (p2 >> 4) & 3, c2 = p2 & 15;
        const int k = 32*s + 8*q2 + t;
        woF[e] = bfc(w_out[k*CZ + 16*(p2 >> 6) + c2] * ln_g[k]);
      }
    }
  }
}

// ---------------------------------------------------------------------------
// Fused main kernel: one block (4 waves) per node, ONE barrier (xh only).
//   E1/E2 gate factors front-loaded into registers (32 dword gathers, latency
//   hidden under rbf phase); kf computed redundantly per wave via 8 MFMAs
//   (C-frag == gate layout, b_edge in C-init); ef A-frags direct from global;
//   no G/kf LDS at all. gate = rcp(1 + E1*E2); b_db in MFMA1 C-init.
// Frag maps: A row=l&15,k=(l>>4)*8+t; B col=l&15,k=(l>>4)*8+t;
//            C col=l&15, row=4*(l>>4)+reg.
// ---------------------------------------------------------------------------
__global__ __launch_bounds__(256, 3) void fused_main_kernel(
    const float* __restrict__ trans, const int* __restrict__ eidx,
    const float* __restrict__ g1, const float* __restrict__ g2,
    const float* __restrict__ ef, const float* __restrict__ b_edge,
    const float* __restrict__ b_db, const float* __restrict__ bias2,
    const unsigned short* __restrict__ wdbF,
    const unsigned short* __restrict__ wedF,
    const unsigned short* __restrict__ woF,
    float* __restrict__ out)
{
  __shared__ unsigned short xh[KNB][72];     // xhat bf16 (transpose for MFMA2)

  const int n = blockIdx.x;
  const int p = threadIdx.x;
  const int w = p >> 6;
  const int l = p & 63;
  const int q = l >> 4;
  const int c = l & 15;
  const int base = n*KNB;

  // ---- front-loaded traffic (all to registers, no LDS deps) -------------
  const int4 eq = *(const int4*)&eidx[base + 4*q];   // gate i-rows (4q+r)
  const int4 ej = *(const int4*)&eidx[base + 4*w];   // j-rows (4w+m)
  const int  sc = eidx[base + c];                    // t_i

  const int eqa[4] = {eq.x, eq.y, eq.z, eq.w};
  const int eja[4] = {ej.x, ej.y, ej.z, ej.w};

  // gate factors: E1[i=4q+r][h=16nt+c], E2[j=4w+m][h=16nt+c]
  float e1v[4][4], e2v[4][4];
  #pragma unroll
  for (int nt = 0; nt < 4; ++nt)
    #pragma unroll
    for (int r = 0; r < 4; ++r) {
      e1v[nt][r] = g1[eqa[r]*CZ + 16*nt + c];
      e2v[nt][r] = g2[eja[r]*CZ + 16*nt + c];
    }

  const float tc0 = trans[sc*3+0], tc1 = trans[sc*3+1], tc2 = trans[sc*3+2];
  float tj[4][3];
  #pragma unroll
  for (int m = 0; m < 4; ++m) {
    tj[m][0] = trans[eja[m]*3+0];
    tj[m][1] = trans[eja[m]*3+1];
    tj[m][2] = trans[eja[m]*3+2];
  }

  // ef A-frags direct from global: row = edge i=c, k = 32s+8q+t
  short8 afe[2];
  #pragma unroll
  for (int s = 0; s < 2; ++s) {
    const float* src = &ef[(base + c)*CZ + 32*s + 8*q];
    const f32x4 x0 = *(const f32x4*)src;
    const f32x4 x1 = *(const f32x4*)(src + 4);
    uint4v u;
    u[0] = pk2(x0[0], x0[1]);
    u[1] = pk2(x0[2], x0[3]);
    u[2] = pk2(x1[0], x1[1]);
    u[3] = pk2(x1[2], x1[3]);
    short8 v;
    __builtin_memcpy(&v, &u, 16);
    afe[s] = v;
  }

  short8 bcur[2];
  #pragma unroll
  for (int s = 0; s < 2; ++s)
    bcur[s] = *(const short8*)&wdbF[(s*4*64 + l)*8];

  const float bo = bias2[16*w + c];
  float bdb[4];
  #pragma unroll
  for (int nt = 0; nt < 4; ++nt) bdb[nt] = b_db[16*nt + c];

  // ---- kf = ef @ w_edge + b_edge, all 4 col-blocks in registers ---------
  f32x4 kfc[4];
  #pragma unroll
  for (int cb = 0; cb < 4; ++cb) {
    const float be = b_edge[16*cb + c];
    kfc[cb] = (f32x4){be, be, be, be};
  }
  #pragma unroll
  for (int s = 0; s < 2; ++s)
    #pragma unroll
    for (int cb = 0; cb < 4; ++cb) {
      const short8 wed = *(const short8*)&wedF[(s*256 + cb*64 + l)*8];
      kfc[cb] = __builtin_amdgcn_mfma_f32_16x16x32_bf16(afe[s], wed, kfc[cb], 0, 0, 0);
    }

  // ---- distances + rbf A-frags (pair i=c, j=4w+m) -----------------------
  const float STEP = 1.2201878439258035f;    // (20/63)*3.2*sqrt(log2e)
  float dsc[4];
  #pragma unroll
  for (int m = 0; m < 4; ++m) {
    const float dx = tc0 - tj[m][0] + 1e-8f;
    const float dy = tc1 - tj[m][1] + 1e-8f;
    const float dz = tc2 - tj[m][2] + 1e-8f;
    dsc[m] = sqrtf(fmaf(dx,dx, fmaf(dy,dy, dz*dz))) * 3.8435917081166394f;
  }
  const float qoff = (float)(8*q) * STEP;
  short8 af[2][4];
  #pragma unroll
  for (int s = 0; s < 2; ++s) {
    const float soff = qoff + (float)(32*s) * STEP;
    #pragma unroll
    for (int m = 0; m < 4; ++m) {
      const float bse = dsc[m] - soff;
      uint4v u;
      #pragma unroll
      for (int t = 0; t < 4; ++t) {
        const float ua = fmaf(-STEP, (float)(2*t),   bse);
        const float ub = fmaf(-STEP, (float)(2*t+1), bse);
        u[t] = pk2(fexp2(-ua*ua), fexp2(-ub*ub));
      }
      short8 v;
      __builtin_memcpy(&v, &u, 16);
      af[s][m] = v;
    }
  }

  // ---- per-nt: MFMA1 (C-init = b_db) + gate + i-reduce, all registers ---
  float upd[4][4];   // [m][nt]
  #pragma unroll
  for (int nt = 0; nt < 4; ++nt) {
    short8 bnext[2];
    if (nt < 3) {
      #pragma unroll
      for (int s = 0; s < 2; ++s)
        bnext[s] = *(const short8*)&wdbF[((s*4 + nt+1)*64 + l)*8];
    }
    const float bdbn = bdb[nt];
    f32x4 acc[4];
    #pragma unroll
    for (int m = 0; m < 4; ++m) acc[m] = (f32x4){bdbn, bdbn, bdbn, bdbn};
    #pragma unroll
    for (int s = 0; s < 2; ++s)
      #pragma unroll
      for (int m = 0; m < 4; ++m)
        acc[m] = __builtin_amdgcn_mfma_f32_16x16x32_bf16(af[s][m], bcur[s], acc[m], 0, 0, 0);

    #pragma unroll
    for (int m = 0; m < 4; ++m) {
      const float e2m = e2v[nt][m];
      float ss = 0.f;
      #pragma unroll
      for (int r = 0; r < 4; ++r) {
        const float gate = __builtin_amdgcn_rcpf(fmaf(e1v[nt][r], e2m, 1.0f));
        ss = fmaf(gate * acc[m][r], kfc[nt][r], ss);
      }
      ss += __shfl_xor(ss, 16);
      ss += __shfl_xor(ss, 32);
      upd[m][nt] = ss;
    }
    if (nt < 3) { bcur[0] = bnext[0]; bcur[1] = bnext[1]; }
  }

  // proj B-frags (hide under LN)
  short8 wb[2];
  #pragma unroll
  for (int s = 0; s < 2; ++s)
    wb[s] = *(const short8*)&woF[(s*256 + p)*8];

  // ---- LayerNorm: q-group q owns row j = 4w+q ---------------------------
  {
    float v[4];
    #pragma unroll
    for (int nt = 0; nt < 4; ++nt)
      v[nt] = (q == 0) ? upd[0][nt] : (q == 1) ? upd[1][nt]
            : (q == 2) ? upd[2][nt] : upd[3][nt];
    float s1 = (v[0] + v[1]) + (v[2] + v[3]);
    float s2 = fmaf(v[0],v[0], fmaf(v[1],v[1], fmaf(v[2],v[2], v[3]*v[3])));
    #pragma unroll
    for (int mk = 1; mk <= 8; mk <<= 1) {
      s1 += __shfl_xor(s1, mk);
      s2 += __shfl_xor(s2, mk);
    }
    const float mean = s1 * 0.015625f;
    const float var  = fmaf(s2, 0.015625f, -mean*mean);
    const float rstd = rsqrtf(var + 1e-5f);
    #pragma unroll
    for (int nt = 0; nt < 4; ++nt)
      xh[4*w + q][16*nt + c] = bfc((v[nt] - mean) * rstd);
  }
  __syncthreads();   // only barrier: xh transpose for MFMA2

  // ---- MFMA2: out = xhat @ (ln_g*w_out) + bias2 -------------------------
  f32x4 acc2 = {};
  #pragma unroll
  for (int s = 0; s < 2; ++s) {
    const short8 a2f = *(const short8*)&xh[c][q*8 + 32*s];
    acc2 = __builtin_amdgcn_mfma_f32_16x16x32_bf16(a2f, wb[s], acc2, 0, 0, 0);
  }
  #pragma unroll
  for (int r = 0; r < 4; ++r)
    out[(base + 4*q + r)*CZ + 16*w + c] = acc2[r] + bo;
}

extern "C" void kernel_launch(void* const* d_in, const int* in_sizes, int n_in,
                              void* d_out, int out_size, void* d_ws, size_t ws_size,
                              hipStream_t stream)
{
  const float* nf     = (const float*)d_in[0];
  const float* trans  = (const float*)d_in[1];
  const float* ef     = (const float*)d_in[2];
  const int*   eidx   = (const int*)d_in[3];
  const float* w_gate = (const float*)d_in[4];
  const float* b_gate = (const float*)d_in[5];
  const float* w_db   = (const float*)d_in[6];
  const float* b_db   = (const float*)d_in[7];
  const float* w_edge = (const float*)d_in[8];
  const float* b_edge = (const float*)d_in[9];
  const float* ln_g   = (const float*)d_in[10];
  const float* ln_b   = (const float*)d_in[11];
  const float* w_out  = (const float*)d_in[12];
  const float* b_out  = (const float*)d_in[13];
  float* out = (float*)d_out;

  float* g1    = (float*)d_ws;                            // E1 [2000][64] f32
  float* g2    = g1 + NND*CZ;                             // E2 [2000][64] f32
  float* bias2 = g2 + NND*CZ;                             // [64] f32
  unsigned short* wdbF = (unsigned short*)(bias2 + CZ);   // 4096 bf16
  unsigned short* wedF = wdbF + 4096;                     // 4096 bf16
  unsigned short* woF  = wedF + 4096;                     // 4096 bf16

  precompute_kernel<<<NND/4 + 1, 256, 0, stream>>>(
      nf, w_gate, b_gate, ln_b, w_out, b_out, w_db, w_edge, ln_g,
      g1, g2, bias2, wdbF, wedF, woF);
  fused_main_kernel<<<NND, 256, 0, stream>>>(
      trans, eidx, g1, g2, ef, b_edge, b_db, bias2,
      wdbF, wedF, woF, out);
}

// Round 14
// 33.686 us; speedup vs baseline: 1.0172x; 1.0172x over previous
//
#include <hip/hip_runtime.h>
#include <hip/hip_bf16.h>

#define NND 2000
#define KNB 16
#define CS 128
#define CZ 64
#define NE (NND*KNB)

typedef __attribute__((ext_vector_type(8))) short short8;
typedef __attribute__((ext_vector_type(4))) float f32x4;
typedef __attribute__((ext_vector_type(2))) unsigned int uint2v;
typedef __attribute__((ext_vector_type(4))) unsigned int uint4v;

// hardware bf16 convert (compiler emits v_cvt_pk_bf16_f32; RNE)
__device__ __forceinline__ unsigned int pk2(float a, float b) {
  __hip_bfloat162 h = __float22bfloat162_rn(make_float2(a, b));
  unsigned int u;
  __builtin_memcpy(&u, &h, 4);
  return u;
}
__device__ __forceinline__ unsigned short bfc(float f) {
  __hip_bfloat16 h = __float2bfloat16(f);
  unsigned short u;
  __builtin_memcpy(&u, &h, 2);
  return u;
}

__device__ __forceinline__ float fexp2(float x) {
#if __has_builtin(__builtin_amdgcn_exp2f)
  return __builtin_amdgcn_exp2f(x);
#else
  return __expf(0.6931471805599453f * x);
#endif
}

// ---------------------------------------------------------------------------
// Precompute (r12, unchanged):
//   blocks [0,500): E1 = exp(-(nf@wg1 + b_gate)), E2 = exp(-(nf@wg2)),
//     w_gate staged once per block into 64KB LDS.
//   block 500: wave0 bias2; wave1 wdbF; wave2 wedF; wave3 woF (bf16 frags).
// ---------------------------------------------------------------------------
__global__ __launch_bounds__(256) void precompute_kernel(
    const float* __restrict__ nf,
    const float* __restrict__ w_gate, const float* __restrict__ b_gate,
    const float* __restrict__ ln_b, const float* __restrict__ w_out,
    const float* __restrict__ b_out,
    const float* __restrict__ w_db, const float* __restrict__ w_edge,
    const float* __restrict__ ln_g,
    float* __restrict__ g1, float* __restrict__ g2, float* __restrict__ bias2,
    unsigned short* __restrict__ wdbF, unsigned short* __restrict__ wedF,
    unsigned short* __restrict__ woF)
{
  __shared__ float wl[2*CS][CZ];        // 64 KB: w_gate staged per block
  const int p = threadIdx.x;
  const int lane = p & 63;
  const int wv   = p >> 6;
  const int b    = blockIdx.x;
  if (b < NND/4) {
    #pragma unroll
    for (int t = 0; t < 16; ++t) {
      const int e = (p + 256*t) * 4;
      const f32x4 x = *(const f32x4*)&w_gate[e];
      *(f32x4*)&wl[e >> 6][e & 63] = x;
    }
    __syncthreads();

    const int v = b*4 + wv;
    const float* nrow = nf + v*CS;
    float a10=0.f,a11=0.f,a12=0.f,a13=0.f;
    float a20=0.f,a21=0.f,a22=0.f,a23=0.f;
    #pragma unroll
    for (int cc = 0; cc < CS; cc += 4) {
      const f32x4 x = *(const f32x4*)&nrow[cc];
      a10 = fmaf(x[0], wl[cc+0][lane], a10);
      a11 = fmaf(x[1], wl[cc+1][lane], a11);
      a12 = fmaf(x[2], wl[cc+2][lane], a12);
      a13 = fmaf(x[3], wl[cc+3][lane], a13);
      a20 = fmaf(x[0], wl[CS+cc+0][lane], a20);
      a21 = fmaf(x[1], wl[CS+cc+1][lane], a21);
      a22 = fmaf(x[2], wl[CS+cc+2][lane], a22);
      a23 = fmaf(x[3], wl[CS+cc+3][lane], a23);
    }
    const float a1 = b_gate[lane] + ((a10+a11)+(a12+a13));
    const float a2 = (a20+a21)+(a22+a23);
    g1[v*CZ + lane] = fexp2(a1 * -1.4426950408889634f);
    g2[v*CZ + lane] = fexp2(a2 * -1.4426950408889634f);
  } else {
    if (wv == 0) {
      float a = b_out[lane];
      #pragma unroll
      for (int cc = 0; cc < CZ; ++cc)
        a = fmaf(ln_b[cc], w_out[cc*CZ + lane], a);
      bias2[lane] = a;
    } else if (wv == 1) {
      for (int e = lane; e < 4096; e += 64) {
        const int entry = e >> 3, t = e & 7;
        const int l2 = entry & 63, sn = entry >> 6;
        const int s = sn >> 2, nt = sn & 3;
        const int q2 = l2 >> 4, c2 = l2 & 15;
        wdbF[e] = bfc(w_db[(32*s + 8*q2 + t)*CZ + 16*nt + c2]);
      }
    } else if (wv == 2) {
      for (int e = lane; e < 4096; e += 64) {
        const int entry = e >> 3, t = e & 7;
        const int p2 = entry & 255, s = entry >> 8;
        const int q2 = (p2 >> 4) & 3, c2 = p2 & 15;
        wedF[e] = bfc(w_edge[(32*s + 8*q2 + t)*CZ + 16*(p2 >> 6) + c2]);
      }
    } else {
      for (int e = lane; e < 4096; e += 64) {
        const int entry = e >> 3, t = e & 7;
        const int p2 = entry & 255, s = entry >> 8;
        const int q2 = (p2 >> 4) & 3, c2 = p2 & 15;
        const int k = 32*s + 8*q2 + t;
        woF[e] = bfc(w_out[k*CZ + 16*(p2 >> 6) + c2] * ln_g[k]);
      }
    }
  }
}

// ---------------------------------------------------------------------------
// Fused main kernel: r12 structure with two de-confounded r13 pieces:
//   (1) kf in registers via 8 redundant MFMAs/wave (b_edge in C-init);
//   (2) ef A-frags direct from global.
//   Gate operands (E1/E2) stay as r12: coalesced f32x4 -> LDS -> in-loop
//   reads. Barriers: 2 (G staging, xh transpose). Gate = rcp(1 + E1*E2).
// Frag maps: A row=l&15,k=(l>>4)*8+t; B col=l&15,k=(l>>4)*8+t;
//            C col=l&15, row=4*(l>>4)+reg.
// ---------------------------------------------------------------------------
__global__ __launch_bounds__(256, 4) void fused_main_kernel(
    const float* __restrict__ trans, const int* __restrict__ eidx,
    const float* __restrict__ g1, const float* __restrict__ g2,
    const float* __restrict__ ef, const float* __restrict__ b_edge,
    const float* __restrict__ b_db, const float* __restrict__ bias2,
    const unsigned short* __restrict__ wdbF,
    const unsigned short* __restrict__ wedF,
    const unsigned short* __restrict__ woF,
    float* __restrict__ out)
{
  __shared__ float G1l[KNB][68];
  __shared__ float G2l[KNB][68];
  __shared__ unsigned short xh[KNB][72];     // xhat bf16 (transpose for MFMA2)

  const int n = blockIdx.x;
  const int p = threadIdx.x;
  const int w = p >> 6;
  const int l = p & 63;
  const int q = l >> 4;
  const int c = l & 15;
  const int base = n*KNB;
  const int r16 = p >> 4, c4 = (p & 15) * 4;

  // ---- front-loaded global traffic --------------------------------------
  const int sr = eidx[base + r16];           // G-row gather index
  const int sc = eidx[base + c];             // t_i index
  int sj[4];
  #pragma unroll
  for (int m = 0; m < 4; ++m) sj[m] = eidx[base + 4*w + m];

  const f32x4 g1row = *(const f32x4*)&g1[sr*CZ + c4];
  const f32x4 g2row = *(const f32x4*)&g2[sr*CZ + c4];

  const float tc0 = trans[sc*3+0], tc1 = trans[sc*3+1], tc2 = trans[sc*3+2];
  float tj[4][3];
  #pragma unroll
  for (int m = 0; m < 4; ++m) {
    tj[m][0] = trans[sj[m]*3+0];
    tj[m][1] = trans[sj[m]*3+1];
    tj[m][2] = trans[sj[m]*3+2];
  }

  // ef A-frags direct from global: row = edge i=c, k = 32s+8q+t
  short8 afe[2];
  #pragma unroll
  for (int s = 0; s < 2; ++s) {
    const float* src = &ef[(base + c)*CZ + 32*s + 8*q];
    const f32x4 x0 = *(const f32x4*)src;
    const f32x4 x1 = *(const f32x4*)(src + 4);
    uint4v u;
    u[0] = pk2(x0[0], x0[1]);
    u[1] = pk2(x0[2], x0[3]);
    u[2] = pk2(x1[0], x1[1]);
    u[3] = pk2(x1[2], x1[3]);
    short8 v;
    __builtin_memcpy(&v, &u, 16);
    afe[s] = v;
  }

  short8 bcur[2];
  #pragma unroll
  for (int s = 0; s < 2; ++s)
    bcur[s] = *(const short8*)&wdbF[(s*4*64 + l)*8];

  const float bo = bias2[16*w + c];
  float bdb[4];
  #pragma unroll
  for (int nt = 0; nt < 4; ++nt) bdb[nt] = b_db[16*nt + c];

  { // stage G rows (register -> LDS, coalesced)
    *(f32x4*)&G1l[r16][c4] = g1row;
    *(f32x4*)&G2l[r16][c4] = g2row;
  }

  // ---- kf = ef @ w_edge + b_edge, all 4 col-blocks in registers ---------
  // (redundant per wave; C-frag kfc[nt][r] = kf[i=4q+r][h=16nt+c])
  f32x4 kfc[4];
  #pragma unroll
  for (int cb = 0; cb < 4; ++cb) {
    const float be = b_edge[16*cb + c];
    kfc[cb] = (f32x4){be, be, be, be};
  }
  #pragma unroll
  for (int s = 0; s < 2; ++s)
    #pragma unroll
    for (int cb = 0; cb < 4; ++cb) {
      const short8 wed = *(const short8*)&wedF[(s*256 + cb*64 + l)*8];
      kfc[cb] = __builtin_amdgcn_mfma_f32_16x16x32_bf16(afe[s], wed, kfc[cb], 0, 0, 0);
    }

  // ---- distances + rbf A-frags (pair i=c, j=4w+m) -----------------------
  const float STEP = 1.2201878439258035f;    // (20/63)*3.2*sqrt(log2e)
  float dsc[4];
  #pragma unroll
  for (int m = 0; m < 4; ++m) {
    const float dx = tc0 - tj[m][0] + 1e-8f;
    const float dy = tc1 - tj[m][1] + 1e-8f;
    const float dz = tc2 - tj[m][2] + 1e-8f;
    dsc[m] = sqrtf(fmaf(dx,dx, fmaf(dy,dy, dz*dz))) * 3.8435917081166394f;
  }
  const float qoff = (float)(8*q) * STEP;
  short8 af[2][4];
  #pragma unroll
  for (int s = 0; s < 2; ++s) {
    const float soff = qoff + (float)(32*s) * STEP;
    #pragma unroll
    for (int m = 0; m < 4; ++m) {
      const float bse = dsc[m] - soff;
      uint4v u;
      #pragma unroll
      for (int t = 0; t < 4; ++t) {
        const float ua = fmaf(-STEP, (float)(2*t),   bse);
        const float ub = fmaf(-STEP, (float)(2*t+1), bse);
        u[t] = pk2(fexp2(-ua*ua), fexp2(-ub*ub));
      }
      short8 v;
      __builtin_memcpy(&v, &u, 16);
      af[s][m] = v;
    }
  }
  __syncthreads();   // b1: G1l/G2l visible

  // ---- per-nt fused MFMA1 + gate + i-reduce -----------------------------
  float upd[4][4];   // [m][nt]
  #pragma unroll
  for (int nt = 0; nt < 4; ++nt) {
    short8 bnext[2];
    if (nt < 3) {
      #pragma unroll
      for (int s = 0; s < 2; ++s)
        bnext[s] = *(const short8*)&wdbF[((s*4 + nt+1)*64 + l)*8];
    }
    float e1v[4];
    #pragma unroll
    for (int r = 0; r < 4; ++r)
      e1v[r] = G1l[4*q + r][16*nt + c];   // E1[i,h]
    const float bdbn = bdb[nt];
    f32x4 acc[4];
    #pragma unroll
    for (int m = 0; m < 4; ++m) acc[m] = (f32x4){bdbn, bdbn, bdbn, bdbn};
    #pragma unroll
    for (int s = 0; s < 2; ++s)
      #pragma unroll
      for (int m = 0; m < 4; ++m)
        acc[m] = __builtin_amdgcn_mfma_f32_16x16x32_bf16(af[s][m], bcur[s], acc[m], 0, 0, 0);

    #pragma unroll
    for (int m = 0; m < 4; ++m) {
      const float e2m = G2l[4*w + m][16*nt + c];   // E2[j,h]
      float ss = 0.f;
      #pragma unroll
      for (int r = 0; r < 4; ++r) {
        const float gate = __builtin_amdgcn_rcpf(fmaf(e1v[r], e2m, 1.0f));
        ss = fmaf(gate * acc[m][r], kfc[nt][r], ss);
      }
      ss += __shfl_xor(ss, 16);
      ss += __shfl_xor(ss, 32);
      upd[m][nt] = ss;
    }
    if (nt < 3) { bcur[0] = bnext[0]; bcur[1] = bnext[1]; }
  }

  // proj B-frags (hide under LN)
  short8 wb[2];
  #pragma unroll
  for (int s = 0; s < 2; ++s)
    wb[s] = *(const short8*)&woF[(s*256 + p)*8];

  // ---- LayerNorm: q-group q owns row j = 4w+q ---------------------------
  {
    float v[4];
    #pragma unroll
    for (int nt = 0; nt < 4; ++nt)
      v[nt] = (q == 0) ? upd[0][nt] : (q == 1) ? upd[1][nt]
            : (q == 2) ? upd[2][nt] : upd[3][nt];
    float s1 = (v[0] + v[1]) + (v[2] + v[3]);
    float s2 = fmaf(v[0],v[0], fmaf(v[1],v[1], fmaf(v[2],v[2], v[3]*v[3])));
    #pragma unroll
    for (int mk = 1; mk <= 8; mk <<= 1) {
      s1 += __shfl_xor(s1, mk);
      s2 += __shfl_xor(s2, mk);
    }
    const float mean = s1 * 0.015625f;
    const float var  = fmaf(s2, 0.015625f, -mean*mean);
    const float rstd = rsqrtf(var + 1e-5f);
    #pragma unroll
    for (int nt = 0; nt < 4; ++nt)
      xh[4*w + q][16*nt + c] = bfc((v[nt] - mean) * rstd);
  }
  __syncthreads();   // b2: xh visible

  // ---- MFMA2: out = xhat @ (ln_g*w_out) + bias2 -------------------------
  f32x4 acc2 = {};
  #pragma unroll
  for (int s = 0; s < 2; ++s) {
    const short8 a2f = *(const short8*)&xh[c][q*8 + 32*s];
    acc2 = __builtin_amdgcn_mfma_f32_16x16x32_bf16(a2f, wb[s], acc2, 0, 0, 0);
  }
  #pragma unroll
  for (int r = 0; r < 4; ++r)
    out[(base + 4*q + r)*CZ + 16*w + c] = acc2[r] + bo;
}

extern "C" void kernel_launch(void* const* d_in, const int* in_sizes, int n_in,
                              void* d_out, int out_size, void* d_ws, size_t ws_size,
                              hipStream_t stream)
{
  const float* nf     = (const float*)d_in[0];
  const float* trans  = (const float*)d_in[1];
  const float* ef     = (const float*)d_in[2];
  const int*   eidx   = (const int*)d_in[3];
  const float* w_gate = (const float*)d_in[4];
  const float* b_gate = (const float*)d_in[5];
  const float* w_db   = (const float*)d_in[6];
  const float* b_db   = (const float*)d_in[7];
  const float* w_edge = (const float*)d_in[8];
  const float* b_edge = (const float*)d_in[9];
  const float* ln_g   = (const float*)d_in[10];
  const float* ln_b   = (const float*)d_in[11];
  const float* w_out  = (const float*)d_in[12];
  const float* b_out  = (const float*)d_in[13];
  float* out = (float*)d_out;

  float* g1    = (float*)d_ws;                            // E1 [2000][64] f32
  float* g2    = g1 + NND*CZ;                             // E2 [2000][64] f32
  float* bias2 = g2 + NND*CZ;                             // [64] f32
  unsigned short* wdbF = (unsigned short*)(bias2 + CZ);   // 4096 bf16
  unsigned short* wedF = wdbF + 4096;                     // 4096 bf16
  unsigned short* woF  = wedF + 4096;                     // 4096 bf16

  precompute_kernel<<<NND/4 + 1, 256, 0, stream>>>(
      nf, w_gate, b_gate, ln_b, w_out, b_out, w_db, w_edge, ln_g,
      g1, g2, bias2, wdbF, wedF, woF);
  fused_main_kernel<<<NND, 256, 0, stream>>>(
      trans, eidx, g1, g2, ef, b_edge, b_db, bias2,
      wdbF, wedF, woF, out);
}

// Round 16
// 29.410 us; speedup vs baseline: 1.1651x; 1.1454x over previous
//
#include <hip/hip_runtime.h>
#include <hip/hip_bf16.h>

#define NND 2000
#define KNB 16
#define CS 128
#define CZ 64
#define NE (NND*KNB)

typedef __attribute__((ext_vector_type(8))) short short8;
typedef __attribute__((ext_vector_type(4))) float f32x4;
typedef __attribute__((ext_vector_type(2))) unsigned int uint2v;
typedef __attribute__((ext_vector_type(4))) unsigned int uint4v;

// hardware bf16 convert (compiler emits v_cvt_pk_bf16_f32; RNE)
__device__ __forceinline__ unsigned int pk2(float a, float b) {
  __hip_bfloat162 h = __float22bfloat162_rn(make_float2(a, b));
  unsigned int u;
  __builtin_memcpy(&u, &h, 4);
  return u;
}
__device__ __forceinline__ unsigned short bfc(float f) {
  __hip_bfloat16 h = __float2bfloat16(f);
  unsigned short u;
  __builtin_memcpy(&u, &h, 2);
  return u;
}

__device__ __forceinline__ float fexp2(float x) {
#if __has_builtin(__builtin_amdgcn_exp2f)
  return __builtin_amdgcn_exp2f(x);
#else
  return __expf(0.6931471805599453f * x);
#endif
}

// ---------------------------------------------------------------------------
// Precompute (r12, unchanged):
//   blocks [0,500): E1 = exp(-(nf@wg1 + b_gate)), E2 = exp(-(nf@wg2)),
//     w_gate staged once per block into 64KB LDS.
//   block 500: wave0 bias2; wave1 wdbF; wave2 wedF; wave3 woF (bf16 frags).
// ---------------------------------------------------------------------------
__global__ __launch_bounds__(256) void precompute_kernel(
    const float* __restrict__ nf,
    const float* __restrict__ w_gate, const float* __restrict__ b_gate,
    const float* __restrict__ ln_b, const float* __restrict__ w_out,
    const float* __restrict__ b_out,
    const float* __restrict__ w_db, const float* __restrict__ w_edge,
    const float* __restrict__ ln_g,
    float* __restrict__ g1, float* __restrict__ g2, float* __restrict__ bias2,
    unsigned short* __restrict__ wdbF, unsigned short* __restrict__ wedF,
    unsigned short* __restrict__ woF)
{
  __shared__ float wl[2*CS][CZ];        // 64 KB: w_gate staged per block
  const int p = threadIdx.x;
  const int lane = p & 63;
  const int wv   = p >> 6;
  const int b    = blockIdx.x;
  if (b < NND/4) {
    #pragma unroll
    for (int t = 0; t < 16; ++t) {
      const int e = (p + 256*t) * 4;
      const f32x4 x = *(const f32x4*)&w_gate[e];
      *(f32x4*)&wl[e >> 6][e & 63] = x;
    }
    __syncthreads();

    const int v = b*4 + wv;
    const float* nrow = nf + v*CS;
    float a10=0.f,a11=0.f,a12=0.f,a13=0.f;
    float a20=0.f,a21=0.f,a22=0.f,a23=0.f;
    #pragma unroll
    for (int cc = 0; cc < CS; cc += 4) {
      const f32x4 x = *(const f32x4*)&nrow[cc];
      a10 = fmaf(x[0], wl[cc+0][lane], a10);
      a11 = fmaf(x[1], wl[cc+1][lane], a11);
      a12 = fmaf(x[2], wl[cc+2][lane], a12);
      a13 = fmaf(x[3], wl[cc+3][lane], a13);
      a20 = fmaf(x[0], wl[CS+cc+0][lane], a20);
      a21 = fmaf(x[1], wl[CS+cc+1][lane], a21);
      a22 = fmaf(x[2], wl[CS+cc+2][lane], a22);
      a23 = fmaf(x[3], wl[CS+cc+3][lane], a23);
    }
    const float a1 = b_gate[lane] + ((a10+a11)+(a12+a13));
    const float a2 = (a20+a21)+(a22+a23);
    g1[v*CZ + lane] = fexp2(a1 * -1.4426950408889634f);
    g2[v*CZ + lane] = fexp2(a2 * -1.4426950408889634f);
  } else {
    if (wv == 0) {
      float a = b_out[lane];
      #pragma unroll
      for (int cc = 0; cc < CZ; ++cc)
        a = fmaf(ln_b[cc], w_out[cc*CZ + lane], a);
      bias2[lane] = a;
    } else if (wv == 1) {
      for (int e = lane; e < 4096; e += 64) {
        const int entry = e >> 3, t = e & 7;
        const int l2 = entry & 63, sn = entry >> 6;
        const int s = sn >> 2, nt = sn & 3;
        const int q2 = l2 >> 4, c2 = l2 & 15;
        wdbF[e] = bfc(w_db[(32*s + 8*q2 + t)*CZ + 16*nt + c2]);
      }
    } else if (wv == 2) {
      for (int e = lane; e < 4096; e += 64) {
        const int entry = e >> 3, t = e & 7;
        const int p2 = entry & 255, s = entry >> 8;
        const int q2 = (p2 >> 4) & 3, c2 = p2 & 15;
        wedF[e] = bfc(w_edge[(32*s + 8*q2 + t)*CZ + 16*(p2 >> 6) + c2]);
      }
    } else {
      for (int e = lane; e < 4096; e += 64) {
        const int entry = e >> 3, t = e & 7;
        const int p2 = entry & 255, s = entry >> 8;
        const int q2 = (p2 >> 4) & 3, c2 = p2 & 15;
        const int k = 32*s + 8*q2 + t;
        woF[e] = bfc(w_out[k*CZ + 16*(p2 >> 6) + c2] * ln_g[k]);
      }
    }
  }
}

// ---------------------------------------------------------------------------
// Fused main kernel: r12 structure verbatim (best: 30.96us), ONE change:
// rbf A-frags via CENTER-START geometric recurrence. Chain starts at t=4
// (chunk center): r4 = exp2(-w^2), w = u-4S; up-ratio gu0 = exp2(2Sw - S^2),
// down-ratio gd0 = exp2(-2Sw - S^2), both *= D = exp2(-2S^2) per step.
// Start value underflows only for |w|>11.2 where ALL true chunk values are
// < 2^-40 -> absolute error <= 1e-12 (the r15 edge-start failure had 7e-3
// errors at sigma-floor LN rows). Clamp u to +-40 keeps gu/gd finite.
// Cost: 3 exp2 + ~18 VALU vs 8 exp2 + 16 VALU per 8-group.
// ---------------------------------------------------------------------------
__global__ __launch_bounds__(256, 4) void fused_main_kernel(
    const float* __restrict__ trans, const int* __restrict__ eidx,
    const float* __restrict__ g1, const float* __restrict__ g2,
    const float* __restrict__ ef, const float* __restrict__ b_edge,
    const float* __restrict__ b_db, const float* __restrict__ bias2,
    const unsigned short* __restrict__ wdbF,
    const unsigned short* __restrict__ wedF,
    const unsigned short* __restrict__ woF,
    float* __restrict__ out)
{
  __shared__ float G1l[KNB][68];
  __shared__ float G2l[KNB][68];
  __shared__ float kfl[KNB][68];
  __shared__ unsigned short xh[KNB][72];     // xhat bf16 (also ef-tile buffer)

  const int n = blockIdx.x;
  const int p = threadIdx.x;
  const int w = p >> 6;
  const int l = p & 63;
  const int q = l >> 4;
  const int c = l & 15;
  const int r16 = p >> 4, c4 = (p & 15) * 4;

  // ---- front-loaded global traffic --------------------------------------
  const int sr = eidx[n*KNB + r16];
  const int sc = eidx[n*KNB + c];
  int sj[4];
  #pragma unroll
  for (int m = 0; m < 4; ++m) sj[m] = eidx[n*KNB + 4*w + m];

  const f32x4 g1row = *(const f32x4*)&g1[sr*CZ + c4];
  const f32x4 g2row = *(const f32x4*)&g2[sr*CZ + c4];
  const f32x4 efrow = *(const f32x4*)&ef[(n*KNB + r16)*CZ + c4];

  const float tc0 = trans[sc*3+0], tc1 = trans[sc*3+1], tc2 = trans[sc*3+2];
  float tj[4][3];
  #pragma unroll
  for (int m = 0; m < 4; ++m) {
    tj[m][0] = trans[sj[m]*3+0];
    tj[m][1] = trans[sj[m]*3+1];
    tj[m][2] = trans[sj[m]*3+2];
  }

  short8 wed[2];
  #pragma unroll
  for (int s = 0; s < 2; ++s)
    wed[s] = *(const short8*)&wedF[(s*256 + p)*8];
  short8 bcur[2];
  #pragma unroll
  for (int s = 0; s < 2; ++s)
    bcur[s] = *(const short8*)&wdbF[(s*4*64 + l)*8];

  const float be = b_edge[16*w + c];
  const float bo = bias2[16*w + c];
  float bdb[4];
  #pragma unroll
  for (int nt = 0; nt < 4; ++nt) bdb[nt] = b_db[16*nt + c];

  // ---- register-only compute while loads land ---------------------------
  const float STEP = 1.2201878439258035f;
  float dsc[4];
  #pragma unroll
  for (int m = 0; m < 4; ++m) {
    const float dx = tc0 - tj[m][0] + 1e-8f;
    const float dy = tc1 - tj[m][1] + 1e-8f;
    const float dz = tc2 - tj[m][2] + 1e-8f;
    dsc[m] = sqrtf(fmaf(dx,dx, fmaf(dy,dy, dz*dz))) * 3.8435917081166394f;
  }
  const float qoff = (float)(8*q) * STEP;

  // rbf A-frags: center-start geometric recurrence (see header comment)
  const float D32 = fexp2(-2.0f * STEP * STEP);      // ratio-of-ratio
  const float S2  = STEP * STEP;
  short8 af[2][4];
  #pragma unroll
  for (int s = 0; s < 2; ++s) {
    const float soff = qoff + (float)(32*s) * STEP;
    #pragma unroll
    for (int m = 0; m < 4; ++m) {
      const float bse = dsc[m] - soff;
      const float u = fmaxf(-40.0f, fminf(40.0f, bse));
      const float wc = u - 4.0f*STEP;                // center-relative
      const float v4 = fexp2(-wc*wc);
      float gu = fexp2(fmaf( 2.0f*STEP, wc, -S2));
      float gd = fexp2(fmaf(-2.0f*STEP, wc, -S2));
      float r = v4;
      r *= gu; const float v5 = r; gu *= D32;
      r *= gu; const float v6 = r; gu *= D32;
      r *= gu; const float v7 = r;
      r = v4;
      r *= gd; const float v3 = r; gd *= D32;
      r *= gd; const float v2 = r; gd *= D32;
      r *= gd; const float v1 = r; gd *= D32;
      r *= gd; const float v0 = r;
      uint4v u4;
      u4[0] = pk2(v0, v1);
      u4[1] = pk2(v2, v3);
      u4[2] = pk2(v4, v5);
      u4[3] = pk2(v6, v7);
      short8 v;
      __builtin_memcpy(&v, &u4, 16);
      af[s][m] = v;
    }
  }

  { // stage ef tile bf16 (into xh) + G rows (register -> LDS)
    uint2v pk;
    pk[0] = pk2(efrow[0], efrow[1]);
    pk[1] = pk2(efrow[2], efrow[3]);
    *(uint2v*)&xh[r16][c4] = pk;
    *(f32x4*)&G1l[r16][c4] = g1row;
    *(f32x4*)&G2l[r16][c4] = g2row;
  }
  __syncthreads();   // b1: ef tile (in xh), G1l, G2l visible

  { // MFMA0: kf tile; wave w owns cols 16w..16w+15
    f32x4 ak = {};
    #pragma unroll
    for (int s = 0; s < 2; ++s) {
      const short8 a0 = *(const short8*)&xh[c][q*8 + 32*s];
      ak = __builtin_amdgcn_mfma_f32_16x16x32_bf16(a0, wed[s], ak, 0, 0, 0);
    }
    #pragma unroll
    for (int r = 0; r < 4; ++r)
      kfl[4*q + r][16*w + c] = ak[r] + be;
  }
  __syncthreads();   // b2: kfl visible (xh free again)

  // ---- per-nt fused MFMA1 + gate + i-reduce -----------------------------
  float upd[4][4];   // [m][nt]
  #pragma unroll
  for (int nt = 0; nt < 4; ++nt) {
    short8 bnext[2];
    if (nt < 3) {
      #pragma unroll
      for (int s = 0; s < 2; ++s)
        bnext[s] = *(const short8*)&wdbF[((s*4 + nt+1)*64 + l)*8];
    }
    float e1v[4], kfv[4];
    #pragma unroll
    for (int r = 0; r < 4; ++r) {
      e1v[r] = G1l[4*q + r][16*nt + c];   // E1[i,h]
      kfv[r] = kfl[4*q + r][16*nt + c];
    }
    const float bdbn = bdb[nt];
    f32x4 acc[4];
    #pragma unroll
    for (int m = 0; m < 4; ++m) acc[m] = (f32x4){bdbn, bdbn, bdbn, bdbn};
    #pragma unroll
    for (int s = 0; s < 2; ++s)
      #pragma unroll
      for (int m = 0; m < 4; ++m)
        acc[m] = __builtin_amdgcn_mfma_f32_16x16x32_bf16(af[s][m], bcur[s], acc[m], 0, 0, 0);

    #pragma unroll
    for (int m = 0; m < 4; ++m) {
      const float e2m = G2l[4*w + m][16*nt + c];   // E2[j,h]
      float ss = 0.f;
      #pragma unroll
      for (int r = 0; r < 4; ++r) {
        const float gate = __builtin_amdgcn_rcpf(fmaf(e1v[r], e2m, 1.0f));
        ss = fmaf(gate * acc[m][r], kfv[r], ss);
      }
      ss += __shfl_xor(ss, 16);
      ss += __shfl_xor(ss, 32);
      upd[m][nt] = ss;
    }
    if (nt < 3) { bcur[0] = bnext[0]; bcur[1] = bnext[1]; }
  }

  // proj B-frags (hide under LN)
  short8 wb[2];
  #pragma unroll
  for (int s = 0; s < 2; ++s)
    wb[s] = *(const short8*)&woF[(s*256 + p)*8];

  // ---- LayerNorm: q-group q owns row j = 4w+q ---------------------------
  {
    float v[4];
    #pragma unroll
    for (int nt = 0; nt < 4; ++nt)
      v[nt] = (q == 0) ? upd[0][nt] : (q == 1) ? upd[1][nt]
            : (q == 2) ? upd[2][nt] : upd[3][nt];
    float s1 = (v[0] + v[1]) + (v[2] + v[3]);
    float s2 = fmaf(v[0],v[0], fmaf(v[1],v[1], fmaf(v[2],v[2], v[3]*v[3])));
    #pragma unroll
    for (int mk = 1; mk <= 8; mk <<= 1) {
      s1 += __shfl_xor(s1, mk);
      s2 += __shfl_xor(s2, mk);
    }
    const float mean = s1 * 0.015625f;
    const float var  = fmaf(s2, 0.015625f, -mean*mean);
    const float rstd = rsqrtf(var + 1e-5f);
    #pragma unroll
    for (int nt = 0; nt < 4; ++nt)
      xh[4*w + q][16*nt + c] = bfc((v[nt] - mean) * rstd);
  }
  __syncthreads();   // b3: xh visible

  // ---- MFMA2: out = xhat @ (ln_g*w_out) + bias2 -------------------------
  f32x4 acc2 = {};
  #pragma unroll
  for (int s = 0; s < 2; ++s) {
    const short8 a2f = *(const short8*)&xh[c][q*8 + 32*s];
    acc2 = __builtin_amdgcn_mfma_f32_16x16x32_bf16(a2f, wb[s], acc2, 0, 0, 0);
  }
  #pragma unroll
  for (int r = 0; r < 4; ++r)
    out[(n*KNB + 4*q + r)*CZ + 16*w + c] = acc2[r] + bo;
}

extern "C" void kernel_launch(void* const* d_in, const int* in_sizes, int n_in,
                              void* d_out, int out_size, void* d_ws, size_t ws_size,
                              hipStream_t stream)
{
  const float* nf     = (const float*)d_in[0];
  const float* trans  = (const float*)d_in[1];
  const float* ef     = (const float*)d_in[2];
  const int*   eidx   = (const int*)d_in[3];
  const float* w_gate = (const float*)d_in[4];
  const float* b_gate = (const float*)d_in[5];
  const float* w_db   = (const float*)d_in[6];
  const float* b_db   = (const float*)d_in[7];
  const float* w_edge = (const float*)d_in[8];
  const float* b_edge = (const float*)d_in[9];
  const float* ln_g   = (const float*)d_in[10];
  const float* ln_b   = (const float*)d_in[11];
  const float* w_out  = (const float*)d_in[12];
  const float* b_out  = (const float*)d_in[13];
  float* out = (float*)d_out;

  float* g1    = (float*)d_ws;                            // E1 [2000][64] f32
  float* g2    = g1 + NND*CZ;                             // E2 [2000][64] f32
  float* bias2 = g2 + NND*CZ;                             // [64] f32
  unsigned short* wdbF = (unsigned short*)(bias2 + CZ);   // 4096 bf16
  unsigned short* wedF = wdbF + 4096;                     // 4096 bf16
  unsigned short* woF  = wedF + 4096;                     // 4096 bf16

  precompute_kernel<<<NND/4 + 1, 256, 0, stream>>>(
      nf, w_gate, b_gate, ln_b, w_out, b_out, w_db, w_edge, ln_g,
      g1, g2, bias2, wdbF, wedF, woF);
  fused_main_kernel<<<NND, 256, 0, stream>>>(
      trans, eidx, g1, g2, ef, b_edge, b_db, bias2,
      wdbF, wedF, woF, out);
}